// Round 1
// baseline (10.997 us; speedup 1.0000x reference)
//
#include <hip/hip_runtime.h>

// SuperGlue loss: B=16, N=M=2048, scores [B, N+1, M+1] f32.
// loss_tp[b] = sum_i scores[b, i, col(gt0[b,i])],  col(-1) -> M (dustbin col)
// loss_tn[b] = sum_{j: gt1[b,j]==-1} scores[b, N, j]   (dustbin row)
// out = mean_b( (-tp[b] - tn[b]) / (cnt1[b] + M) )

#define BB 16
#define NN 2048
#define MM 2048
#define CHUNKS 4          // chunks per batch
#define TPB 512           // threads per block == chunk size
#define NBLK (BB * CHUNKS)

__global__ __launch_bounds__(TPB) void sg_partial(
    const int* __restrict__ gt0,       // [B, N]
    const int* __restrict__ gt1,       // [B, M]
    const float* __restrict__ scores,  // [B, N+1, M+1]
    double* __restrict__ ws_sum,       // [NBLK]
    int* __restrict__ ws_cnt)          // [NBLK]
{
    const int blk = blockIdx.x;            // 0..NBLK-1
    const int b   = blk / CHUNKS;
    const int c   = blk % CHUNKS;
    const int tid = threadIdx.x;           // 0..TPB-1
    const int idx = c * TPB + tid;         // element index in [0, N)
    const long long bofs = (long long)b * (long long)(NN + 1) * (MM + 1);

    double s = 0.0;
    int cnt = 0;

    // tp contribution: scores[b, idx, col]
    {
        int g = gt0[b * NN + idx];
        int col = (g < 0) ? MM : g;        // torch -1 wraps to last column
        s += (double)scores[bofs + (long long)idx * (MM + 1) + col];
    }
    // tn contribution: dustbin row N at column idx where gt1 == -1
    {
        int g = gt1[b * MM + idx];
        if (g == -1) {
            s += (double)scores[bofs + (long long)NN * (MM + 1) + idx];
            cnt += 1;
        }
    }

    // wave (64-lane) reduction
    #pragma unroll
    for (int off = 32; off > 0; off >>= 1) {
        s   += __shfl_down(s, off, 64);
        cnt += __shfl_down(cnt, off, 64);
    }
    __shared__ double ls[TPB / 64];
    __shared__ int    lc[TPB / 64];
    const int wave = tid >> 6;
    const int lane = tid & 63;
    if (lane == 0) { ls[wave] = s; lc[wave] = cnt; }
    __syncthreads();
    if (wave == 0) {
        s   = (lane < TPB / 64) ? ls[lane] : 0.0;
        cnt = (lane < TPB / 64) ? lc[lane] : 0;
        #pragma unroll
        for (int off = 4; off > 0; off >>= 1) {
            s   += __shfl_down(s, off, 64);
            cnt += __shfl_down(cnt, off, 64);
        }
        if (lane == 0) {
            ws_sum[blk] = s;
            ws_cnt[blk] = cnt;
        }
    }
}

__global__ __launch_bounds__(64) void sg_final(
    const double* __restrict__ ws_sum,
    const int* __restrict__ ws_cnt,
    float* __restrict__ out)
{
    const int lane = threadIdx.x;  // one wave
    double term = 0.0;
    if (lane < BB) {
        double s = 0.0;
        int cnt = 0;
        #pragma unroll
        for (int c = 0; c < CHUNKS; ++c) {
            s   += ws_sum[lane * CHUNKS + c];
            cnt += ws_cnt[lane * CHUNKS + c];
        }
        term = (-s) / (double)(cnt + MM);
    }
    #pragma unroll
    for (int off = 32; off > 0; off >>= 1)
        term += __shfl_down(term, off, 64);
    if (lane == 0) out[0] = (float)(term / (double)BB);
}

extern "C" void kernel_launch(void* const* d_in, const int* in_sizes, int n_in,
                              void* d_out, int out_size, void* d_ws, size_t ws_size,
                              hipStream_t stream) {
    const int*   gt0    = (const int*)d_in[0];
    const int*   gt1    = (const int*)d_in[1];
    const float* scores = (const float*)d_in[2];

    double* ws_sum = (double*)d_ws;                                   // 64 * 8 B
    int*    ws_cnt = (int*)((char*)d_ws + NBLK * sizeof(double));     // 64 * 4 B

    sg_partial<<<NBLK, TPB, 0, stream>>>(gt0, gt1, scores, ws_sum, ws_cnt);
    sg_final<<<1, 64, 0, stream>>>(ws_sum, ws_cnt, (float*)d_out);
}